// Round 1
// baseline (441.049 us; speedup 1.0000x reference)
//
#include <hip/hip_runtime.h>
#include <math.h>

#define NB 4
#define CC 256
#define HWD 4096

// -------------------- kernel 1: per-pixel reciprocal L2 norm --------------------
// grid.x = NB*HWD/256, grid.y = 2 (0 -> rgb, 1 -> ir)
__global__ __launch_bounds__(256) void norm_kernel(
    const float* __restrict__ rgb, const float* __restrict__ ir,
    float* __restrict__ rnorm_r, float* __restrict__ rnorm_i)
{
    const float* src = blockIdx.y ? ir : rgb;
    float* dst = blockIdx.y ? rnorm_i : rnorm_r;
    int P = blockIdx.x * 256 + threadIdx.x;      // 0..NB*HWD-1
    int n = P >> 12;
    int p = P & (HWD - 1);
    const float* base = src + ((size_t)n * CC) * HWD + p;
    float ss = 0.f;
#pragma unroll 4
    for (int c = 0; c < CC; ++c) {
        float x = base[(size_t)c * HWD];
        ss = fmaf(x, x, ss);
    }
    dst[P] = 1.0f / fmaxf(sqrtf(ss), 1e-12f);
}

// -------------------- kernel 2: fused GEMM + exp + masked row/col sums --------------------
// S[p][q] = sum_c An[c][p] * Bn[c][q]; e = exp(clamp(S,-1,1)*20)
// row sums (over q): den_r, num_r (mask rm[p]==im[q]) ; col sums (over p): den_i, num_i
__global__ __launch_bounds__(256) void gemm_fused(
    const float* __restrict__ A, const float* __restrict__ B,
    const float* __restrict__ rnorm_r, const float* __restrict__ rnorm_i,
    const int* __restrict__ rmask, const int* __restrict__ imask,
    float* __restrict__ num_r, float* __restrict__ den_r,
    float* __restrict__ num_i, float* __restrict__ den_i)
{
    __shared__ float As[16][128];
    __shared__ float Bs[16][128];
    __shared__ float colbuf[4][2][128];

    const int n  = blockIdx.z;
    const int p0 = blockIdx.y * 128;
    const int q0 = blockIdx.x * 128;
    const int t  = threadIdx.x;
    const int tx = t & 15, ty = t >> 4;
    const int lr = t >> 5;            // 0..7
    const int lc = (t & 31) << 2;     // 0,4,...,124

    const float* Abase = A + ((size_t)n * CC) * HWD + p0 + lc;
    const float* Bbase = B + ((size_t)n * CC) * HWD + q0 + lc;
    const float4 ra = *(const float4*)(rnorm_r + (size_t)n * HWD + p0 + lc);
    const float4 rb = *(const float4*)(rnorm_i + (size_t)n * HWD + q0 + lc);

    float acc[8][8];
#pragma unroll
    for (int i = 0; i < 8; ++i)
#pragma unroll
        for (int j = 0; j < 8; ++j) acc[i][j] = 0.f;

    for (int c0 = 0; c0 < CC; c0 += 16) {
        float4 a0 = *(const float4*)(Abase + (size_t)(c0 + lr) * HWD);
        float4 a1 = *(const float4*)(Abase + (size_t)(c0 + lr + 8) * HWD);
        float4 b0 = *(const float4*)(Bbase + (size_t)(c0 + lr) * HWD);
        float4 b1 = *(const float4*)(Bbase + (size_t)(c0 + lr + 8) * HWD);
        a0.x *= ra.x; a0.y *= ra.y; a0.z *= ra.z; a0.w *= ra.w;
        a1.x *= ra.x; a1.y *= ra.y; a1.z *= ra.z; a1.w *= ra.w;
        b0.x *= rb.x; b0.y *= rb.y; b0.z *= rb.z; b0.w *= rb.w;
        b1.x *= rb.x; b1.y *= rb.y; b1.z *= rb.z; b1.w *= rb.w;
        __syncthreads();
        *(float4*)&As[lr][lc]     = a0;
        *(float4*)&As[lr + 8][lc] = a1;
        *(float4*)&Bs[lr][lc]     = b0;
        *(float4*)&Bs[lr + 8][lc] = b1;
        __syncthreads();
#pragma unroll
        for (int k = 0; k < 16; ++k) {
            float4 av0 = *(const float4*)&As[k][ty * 4];
            float4 av1 = *(const float4*)&As[k][64 + ty * 4];
            float4 bv0 = *(const float4*)&Bs[k][tx * 4];
            float4 bv1 = *(const float4*)&Bs[k][64 + tx * 4];
            float ar[8] = {av0.x, av0.y, av0.z, av0.w, av1.x, av1.y, av1.z, av1.w};
            float br[8] = {bv0.x, bv0.y, bv0.z, bv0.w, bv1.x, bv1.y, bv1.z, bv1.w};
#pragma unroll
            for (int i = 0; i < 8; ++i)
#pragma unroll
                for (int j = 0; j < 8; ++j)
                    acc[i][j] = fmaf(ar[i], br[j], acc[i][j]);
        }
    }

    // ---- epilogue: clamp, exp, mask, reduce ----
    int rlab[8], clab[8];
#pragma unroll
    for (int i = 0; i < 8; ++i) {
        int R = ty * 4 + (i & 3) + (i >> 2) * 64;
        rlab[i] = rmask[(size_t)n * HWD + p0 + R];
    }
#pragma unroll
    for (int j = 0; j < 8; ++j) {
        int Cq = tx * 4 + (j & 3) + (j >> 2) * 64;
        clab[j] = imask[(size_t)n * HWD + q0 + Cq];
    }

    float rn[8], rd[8], cn[8], cd[8];
#pragma unroll
    for (int i = 0; i < 8; ++i) { rn[i] = 0.f; rd[i] = 0.f; cn[i] = 0.f; cd[i] = 0.f; }

#pragma unroll
    for (int i = 0; i < 8; ++i) {
#pragma unroll
        for (int j = 0; j < 8; ++j) {
            float s = fminf(fmaxf(acc[i][j], -1.0f), 1.0f);
            float e = __expf(s * 20.0f);
            rd[i] += e;
            cd[j] += e;
            if (rlab[i] == clab[j]) { rn[i] += e; cn[j] += e; }
        }
    }

    // row reduction over tx (lane bits 0..3)
#pragma unroll
    for (int i = 0; i < 8; ++i) {
        rn[i] += __shfl_xor(rn[i], 1); rn[i] += __shfl_xor(rn[i], 2);
        rn[i] += __shfl_xor(rn[i], 4); rn[i] += __shfl_xor(rn[i], 8);
        rd[i] += __shfl_xor(rd[i], 1); rd[i] += __shfl_xor(rd[i], 2);
        rd[i] += __shfl_xor(rd[i], 4); rd[i] += __shfl_xor(rd[i], 8);
    }
    if (tx == 0) {
#pragma unroll
        for (int i = 0; i < 8; ++i) {
            int R = ty * 4 + (i & 3) + (i >> 2) * 64;
            atomicAdd(&num_r[(size_t)n * HWD + p0 + R], rn[i]);
            atomicAdd(&den_r[(size_t)n * HWD + p0 + R], rd[i]);
        }
    }

    // column reduction: over ty-in-wave (lane bits 4,5), then cross-wave via LDS
#pragma unroll
    for (int j = 0; j < 8; ++j) {
        cn[j] += __shfl_xor(cn[j], 16); cn[j] += __shfl_xor(cn[j], 32);
        cd[j] += __shfl_xor(cd[j], 16); cd[j] += __shfl_xor(cd[j], 32);
    }
    int lane = t & 63, wave = t >> 6;
    if (lane < 16) {
#pragma unroll
        for (int j = 0; j < 8; ++j) {
            int Cq = tx * 4 + (j & 3) + (j >> 2) * 64;
            colbuf[wave][0][Cq] = cn[j];
            colbuf[wave][1][Cq] = cd[j];
        }
    }
    __syncthreads();
    if (t < 128) {
        float sn = colbuf[0][0][t] + colbuf[1][0][t] + colbuf[2][0][t] + colbuf[3][0][t];
        float sd = colbuf[0][1][t] + colbuf[1][1][t] + colbuf[2][1][t] + colbuf[3][1][t];
        atomicAdd(&num_i[(size_t)n * HWD + q0 + t], sn);
        atomicAdd(&den_i[(size_t)n * HWD + q0 + t], sd);
    }
}

// -------------------- kernel 3: loss entries + global reduce --------------------
__global__ __launch_bounds__(256) void loss_reduce(
    const float* __restrict__ num_r, const float* __restrict__ den_r,
    const float* __restrict__ num_i, const float* __restrict__ den_i,
    const int* __restrict__ rmask, const int* __restrict__ imask,
    float* __restrict__ accum)
{
    __shared__ float sbuf[2][4];
    int idx = blockIdx.x * 256 + threadIdx.x;   // 0 .. 2*NB*HWD-1
    float num, den; int fg;
    if (idx < NB * HWD) {
        num = num_r[idx]; den = den_r[idx]; fg = rmask[idx] > 0;
    } else {
        int k = idx - NB * HWD;
        num = num_i[k]; den = den_i[k]; fg = imask[k] > 0;
    }
    float v = 0.f, cnt = 0.f;
    if (fg && num > 0.f) {
        float r = num / (den + 1e-6f);
        v = -__logf(r);
        cnt = 1.f;
    }
#pragma unroll
    for (int m = 1; m <= 32; m <<= 1) {
        v += __shfl_xor(v, m);
        cnt += __shfl_xor(cnt, m);
    }
    int lane = threadIdx.x & 63, wave = threadIdx.x >> 6;
    if (lane == 0) { sbuf[0][wave] = v; sbuf[1][wave] = cnt; }
    __syncthreads();
    if (threadIdx.x == 0) {
        atomicAdd(&accum[0], sbuf[0][0] + sbuf[0][1] + sbuf[0][2] + sbuf[0][3]);
        atomicAdd(&accum[1], sbuf[1][0] + sbuf[1][1] + sbuf[1][2] + sbuf[1][3]);
    }
}

__global__ void finalize(const float* __restrict__ accum, float* __restrict__ out) {
    out[0] = accum[0] / fmaxf(accum[1], 1.0f);
}

// -------------------- launch --------------------
extern "C" void kernel_launch(void* const* d_in, const int* in_sizes, int n_in,
                              void* d_out, int out_size, void* d_ws, size_t ws_size,
                              hipStream_t stream) {
    const float* rgb = (const float*)d_in[0];
    const float* ir  = (const float*)d_in[1];
    const int* rm = (const int*)d_in[2];
    const int* im = (const int*)d_in[3];
    float* out = (float*)d_out;
    float* ws = (float*)d_ws;

    const size_t NP = (size_t)NB * HWD;   // 16384 pixels
    float* rnorm_r = ws;                  // NP
    float* rnorm_i = rnorm_r + NP;        // NP
    float* num_r   = rnorm_i + NP;        // NP
    float* den_r   = num_r + NP;
    float* num_i   = den_r + NP;
    float* den_i   = num_i + NP;
    float* accum   = den_i + NP;          // 2 floats

    // zero num/den (4*NP) + accum (2)
    hipMemsetAsync(num_r, 0, (4 * NP + 2) * sizeof(float), stream);

    norm_kernel<<<dim3(NP / 256, 2), 256, 0, stream>>>(rgb, ir, rnorm_r, rnorm_i);
    gemm_fused<<<dim3(HWD / 128, HWD / 128, NB), 256, 0, stream>>>(
        rgb, ir, rnorm_r, rnorm_i, rm, im, num_r, den_r, num_i, den_i);
    loss_reduce<<<(2 * NP) / 256, 256, 0, stream>>>(num_r, den_r, num_i, den_i, rm, im, accum);
    finalize<<<1, 1, 0, stream>>>(accum, out);
}

// Round 2
// 183.277 us; speedup vs baseline: 2.4065x; 2.4065x over previous
//
#include <hip/hip_runtime.h>
#include <math.h>
#include <stdint.h>

#define NB 4
#define CC 256
#define HWD 4096

typedef __attribute__((ext_vector_type(8))) short bf16x8;
typedef __attribute__((ext_vector_type(4))) float f32x4;

__device__ __forceinline__ void gload16(const void* g, void* l) {
    using GP = const __attribute__((address_space(1))) uint32_t*;
    using LP = __attribute__((address_space(3))) uint32_t*;
    __builtin_amdgcn_global_load_lds((GP)g, (LP)l, 16, 0, 0);
}

// ---------------- kernel 1: per-pixel L2 norm + scale + bf16 + transpose ----------------
// in : src[n][c][p] fp32 (c-major), out: dst[n*HWD + p][c] bf16 (c contiguous)
// block: 256 threads = 32 pixels x 8 channel-groups of 32
__global__ __launch_bounds__(256) void normcvt(
    const float* __restrict__ rgb, const float* __restrict__ ir,
    ushort* __restrict__ Abf, ushort* __restrict__ Bbf)
{
    __shared__ float ssbuf[8][32];
    __shared__ float rnl[32];
    const float* src = blockIdx.y ? ir : rgb;
    ushort* dst = blockIdx.y ? Bbf : Abf;
    const int t = threadIdx.x;
    const int p = t & 31, sg = t >> 5;
    const int P = blockIdx.x * 32 + p;          // 0 .. NB*HWD-1
    const int n = P >> 12, pl = P & (HWD - 1);
    const float* base = src + ((size_t)n * CC) * HWD + pl;
    const int c0 = sg * 32;

    float ss = 0.f;
#pragma unroll
    for (int i = 0; i < 32; ++i) {
        float x = base[(size_t)(c0 + i) * HWD];
        ss = fmaf(x, x, ss);
    }
    ssbuf[sg][p] = ss;
    __syncthreads();
    if (t < 32) {
        float s2 = 0.f;
#pragma unroll
        for (int g = 0; g < 8; ++g) s2 += ssbuf[g][t];
        rnl[t] = 1.0f / fmaxf(sqrtf(s2), 1e-12f);
    }
    __syncthreads();
    const float rn = rnl[p];

    uint pk[16];
#pragma unroll
    for (int i = 0; i < 16; ++i) {
        float x0 = base[(size_t)(c0 + 2 * i) * HWD] * rn;
        float x1 = base[(size_t)(c0 + 2 * i + 1) * HWD] * rn;
        uint u0 = __float_as_uint(x0); u0 += 0x7fffu + ((u0 >> 16) & 1u);  // RNE bf16
        uint u1 = __float_as_uint(x1); u1 += 0x7fffu + ((u1 >> 16) & 1u);
        pk[i] = (u0 >> 16) | (u1 & 0xffff0000u);
    }
    uint4* o = (uint4*)(dst + (size_t)P * CC + c0);
#pragma unroll
    for (int k = 0; k < 4; ++k)
        o[k] = make_uint4(pk[4 * k], pk[4 * k + 1], pk[4 * k + 2], pk[4 * k + 3]);
}

// ---------------- kernel 2: bf16 MFMA GEMM + exp + masked row/col sums ----------------
// S[p][q] = sum_c A[p][c]*B[q][c]; tiles 128x128, 4 waves (2x2 of 64x64), BK=32
__global__ __launch_bounds__(256) void gemm_mfma(
    const ushort* __restrict__ Abf, const ushort* __restrict__ Bbf,
    const int* __restrict__ rmask, const int* __restrict__ imask,
    float* __restrict__ num_r, float* __restrict__ den_r,
    float* __restrict__ num_i, float* __restrict__ den_i)
{
    __shared__ ushort As[2][128][32];
    __shared__ ushort Bs[2][128][32];

    const int n  = blockIdx.z;
    const int p0 = blockIdx.y * 128;
    const int q0 = blockIdx.x * 128;
    const int t  = threadIdx.x;
    const int lane = t & 63;
    const int wv = t >> 6, wr = wv >> 1, wc = wv & 1;
    const int kg = lane >> 4, rl = lane & 15;

    const ushort* Ab = Abf + ((size_t)n * HWD + p0) * CC;
    const ushort* Bb = Bbf + ((size_t)n * HWD + q0) * CC;

    f32x4 acc[4][4];
#pragma unroll
    for (int mi = 0; mi < 4; ++mi)
#pragma unroll
        for (int ni = 0; ni < 4; ++ni) acc[mi][ni] = (f32x4){0.f, 0.f, 0.f, 0.f};

    // staging: 512 slots of 16B per matrix; slot -> row r=slot/4, chunk s=slot&3.
    // LDS linear (global_load_lds), global chunk pre-swizzled: g = s ^ ((r>>1)&3)
    auto stage = [&](int buf, int c0) {
#pragma unroll
        for (int it = 0; it < 2; ++it) {
            int slot = it * 256 + t;
            int r = slot >> 2, s = slot & 3;
            int g = s ^ ((r >> 1) & 3);
            const ushort* ga = Ab + (size_t)r * CC + c0 + g * 8;
            const ushort* gb = Bb + (size_t)r * CC + c0 + g * 8;
            char* la = ((char*)&As[buf][0][0]) + (size_t)(it * 256 + (t & 192)) * 16;
            char* lb = ((char*)&Bs[buf][0][0]) + (size_t)(it * 256 + (t & 192)) * 16;
            gload16(ga, la);
            gload16(gb, lb);
        }
    };

    stage(0, 0);
    for (int kt = 0; kt < 8; ++kt) {
        __syncthreads();                       // stage for kt complete (vmcnt(0) drain)
        if (kt < 7) stage((kt + 1) & 1, (kt + 1) * 32);
        const int buf = kt & 1;
        bf16x8 a[4], b[4];
#pragma unroll
        for (int mi = 0; mi < 4; ++mi) {
            int r = wr * 64 + mi * 16 + rl;
            int s = kg ^ ((r >> 1) & 3);
            a[mi] = *(const bf16x8*)&As[buf][r][s * 8];
        }
#pragma unroll
        for (int ni = 0; ni < 4; ++ni) {
            int r = wc * 64 + ni * 16 + rl;
            int s = kg ^ ((r >> 1) & 3);
            b[ni] = *(const bf16x8*)&Bs[buf][r][s * 8];
        }
#pragma unroll
        for (int mi = 0; mi < 4; ++mi)
#pragma unroll
            for (int ni = 0; ni < 4; ++ni)
                acc[mi][ni] = __builtin_amdgcn_mfma_f32_16x16x32_bf16(a[mi], b[ni], acc[mi][ni], 0, 0, 0);
    }

    // ---- epilogue ----
    // C/D layout: col = lane&15 -> q0+wc*64+ni*16+rl ; row = kg*4+j -> p0+wr*64+mi*16+kg*4+j
    const int* rmp = rmask + (size_t)n * HWD + p0 + wr * 64;
    const int* imp = imask + (size_t)n * HWD + q0 + wc * 64;
    int clab[4];
#pragma unroll
    for (int ni = 0; ni < 4; ++ni) clab[ni] = imp[ni * 16 + rl];

    const float SC = 28.853900817779268f;      // 20 * log2(e)
    float cn[4] = {0.f, 0.f, 0.f, 0.f}, cd[4] = {0.f, 0.f, 0.f, 0.f};

#pragma unroll
    for (int mi = 0; mi < 4; ++mi) {
        int4 r4 = *(const int4*)(rmp + mi * 16 + kg * 4);
        int rlab[4] = {r4.x, r4.y, r4.z, r4.w};
        float rn4[4] = {0.f, 0.f, 0.f, 0.f}, rd4[4] = {0.f, 0.f, 0.f, 0.f};
#pragma unroll
        for (int ni = 0; ni < 4; ++ni) {
#pragma unroll
            for (int j = 0; j < 4; ++j) {
                float s = fminf(fmaxf(acc[mi][ni][j], -1.f), 1.f);
                float e = exp2f(s * SC);
                rd4[j] += e;
                cd[ni] += e;
                bool m = (rlab[j] == clab[ni]);
                rn4[j] += m ? e : 0.f;
                cn[ni] += m ? e : 0.f;
            }
        }
#pragma unroll
        for (int j = 0; j < 4; ++j) {
            rn4[j] += __shfl_xor(rn4[j], 1); rn4[j] += __shfl_xor(rn4[j], 2);
            rn4[j] += __shfl_xor(rn4[j], 4); rn4[j] += __shfl_xor(rn4[j], 8);
            rd4[j] += __shfl_xor(rd4[j], 1); rd4[j] += __shfl_xor(rd4[j], 2);
            rd4[j] += __shfl_xor(rd4[j], 4); rd4[j] += __shfl_xor(rd4[j], 8);
        }
        if (rl == 0) {
            size_t row = (size_t)n * HWD + p0 + wr * 64 + mi * 16 + kg * 4;
#pragma unroll
            for (int j = 0; j < 4; ++j) {
                atomicAdd(&num_r[row + j], rn4[j]);
                atomicAdd(&den_r[row + j], rd4[j]);
            }
        }
    }
#pragma unroll
    for (int ni = 0; ni < 4; ++ni) {
        cn[ni] += __shfl_xor(cn[ni], 16); cn[ni] += __shfl_xor(cn[ni], 32);
        cd[ni] += __shfl_xor(cd[ni], 16); cd[ni] += __shfl_xor(cd[ni], 32);
    }
    if (kg == 0) {
#pragma unroll
        for (int ni = 0; ni < 4; ++ni) {
            size_t col = (size_t)n * HWD + q0 + wc * 64 + ni * 16 + rl;
            atomicAdd(&num_i[col], cn[ni]);
            atomicAdd(&den_i[col], cd[ni]);
        }
    }
}

// ---------------- kernel 3: loss entries + global reduce ----------------
__global__ __launch_bounds__(256) void loss_reduce(
    const float* __restrict__ num_r, const float* __restrict__ den_r,
    const float* __restrict__ num_i, const float* __restrict__ den_i,
    const int* __restrict__ rmask, const int* __restrict__ imask,
    float* __restrict__ accum)
{
    __shared__ float sbuf[2][4];
    int idx = blockIdx.x * 256 + threadIdx.x;   // 0 .. 2*NB*HWD-1
    float num, den; int fg;
    if (idx < NB * HWD) {
        num = num_r[idx]; den = den_r[idx]; fg = rmask[idx] > 0;
    } else {
        int k = idx - NB * HWD;
        num = num_i[k]; den = den_i[k]; fg = imask[k] > 0;
    }
    float v = 0.f, cnt = 0.f;
    if (fg && num > 0.f) {
        float r = num / (den + 1e-6f);
        v = -__logf(r);
        cnt = 1.f;
    }
#pragma unroll
    for (int m = 1; m <= 32; m <<= 1) {
        v += __shfl_xor(v, m);
        cnt += __shfl_xor(cnt, m);
    }
    int lane = threadIdx.x & 63, wave = threadIdx.x >> 6;
    if (lane == 0) { sbuf[0][wave] = v; sbuf[1][wave] = cnt; }
    __syncthreads();
    if (threadIdx.x == 0) {
        atomicAdd(&accum[0], sbuf[0][0] + sbuf[0][1] + sbuf[0][2] + sbuf[0][3]);
        atomicAdd(&accum[1], sbuf[1][0] + sbuf[1][1] + sbuf[1][2] + sbuf[1][3]);
    }
}

__global__ void finalize(const float* __restrict__ accum, float* __restrict__ out) {
    out[0] = accum[0] / fmaxf(accum[1], 1.0f);
}

// ---------------- launch ----------------
extern "C" void kernel_launch(void* const* d_in, const int* in_sizes, int n_in,
                              void* d_out, int out_size, void* d_ws, size_t ws_size,
                              hipStream_t stream) {
    const float* rgb = (const float*)d_in[0];
    const float* ir  = (const float*)d_in[1];
    const int* rm = (const int*)d_in[2];
    const int* im = (const int*)d_in[3];
    float* out = (float*)d_out;

    const size_t NP = (size_t)NB * HWD;          // 16384 pixels
    const size_t NE = NP * CC;                   // 4M bf16 per array
    ushort* Abf = (ushort*)d_ws;
    ushort* Bbf = Abf + NE;
    float* num_r = (float*)(Bbf + NE);
    float* den_r = num_r + NP;
    float* num_i = den_r + NP;
    float* den_i = num_i + NP;
    float* accum = den_i + NP;                   // 2 floats

    hipMemsetAsync(num_r, 0, (4 * NP + 2) * sizeof(float), stream);

    normcvt<<<dim3(NP / 32, 2), 256, 0, stream>>>(rgb, ir, Abf, Bbf);
    gemm_mfma<<<dim3(HWD / 128, HWD / 128, NB), 256, 0, stream>>>(
        Abf, Bbf, rm, im, num_r, den_r, num_i, den_i);
    loss_reduce<<<(2 * NP) / 256, 256, 0, stream>>>(num_r, den_r, num_i, den_i, rm, im, accum);
    finalize<<<1, 1, 0, stream>>>(accum, out);
}

// Round 3
// 166.242 us; speedup vs baseline: 2.6531x; 1.1025x over previous
//
#include <hip/hip_runtime.h>
#include <math.h>
#include <stdint.h>

#define NB 4
#define CC 256
#define HWD 4096

typedef __attribute__((ext_vector_type(8))) short bf16x8;
typedef __attribute__((ext_vector_type(4))) float f32x4;

__device__ __forceinline__ void gload16(const void* g, void* l) {
    using GP = const __attribute__((address_space(1))) uint32_t*;
    using LP = __attribute__((address_space(3))) uint32_t*;
    __builtin_amdgcn_global_load_lds((GP)g, (LP)l, 16, 0, 0);
}

// sum over each 16-lane DPP row; result valid in lane (rl==15) of each row
__device__ __forceinline__ float dpp_rowsum16(float v) {
    v += __int_as_float(__builtin_amdgcn_update_dpp(0, __float_as_int(v), 0x111, 0xf, 0xf, true)); // row_shr:1
    v += __int_as_float(__builtin_amdgcn_update_dpp(0, __float_as_int(v), 0x112, 0xf, 0xf, true)); // row_shr:2
    v += __int_as_float(__builtin_amdgcn_update_dpp(0, __float_as_int(v), 0x114, 0xf, 0xf, true)); // row_shr:4
    v += __int_as_float(__builtin_amdgcn_update_dpp(0, __float_as_int(v), 0x118, 0xf, 0xf, true)); // row_shr:8
    return v;
}

// ---------------- kernel 1: per-pixel L2 norm + scale + bf16 + transpose ----------------
// in : src[n][c][p] fp32 (c-major), out: dst[n*HWD + p][c] bf16 (c contiguous)
// block: 512 threads = 64 pixels x 8 channel-groups of 32; values kept in regs between passes
__global__ __launch_bounds__(512) void normcvt(
    const float* __restrict__ rgb, const float* __restrict__ ir,
    ushort* __restrict__ Abf, ushort* __restrict__ Bbf)
{
    __shared__ float ssbuf[8][64];
    __shared__ float rnl[64];
    const float* src = blockIdx.y ? ir : rgb;
    ushort* dst = blockIdx.y ? Bbf : Abf;
    const int t = threadIdx.x;
    const int p = t & 63, sg = t >> 6;
    const int P = blockIdx.x * 64 + p;          // 0 .. NB*HWD-1
    const int n = P >> 12, pl = P & (HWD - 1);
    const float* base = src + ((size_t)n * CC) * HWD + pl;
    const int c0 = sg * 32;

    float x[32];
    float ss = 0.f;
#pragma unroll
    for (int i = 0; i < 32; ++i) {
        x[i] = base[(size_t)(c0 + i) * HWD];
        ss = fmaf(x[i], x[i], ss);
    }
    ssbuf[sg][p] = ss;
    __syncthreads();
    if (t < 64) {
        float s2 = 0.f;
#pragma unroll
        for (int g = 0; g < 8; ++g) s2 += ssbuf[g][t];
        rnl[t] = 1.0f / fmaxf(sqrtf(s2), 1e-12f);
    }
    __syncthreads();
    const float rn = rnl[p];

    uint pk[16];
#pragma unroll
    for (int i = 0; i < 16; ++i) {
        float x0 = x[2 * i] * rn;
        float x1 = x[2 * i + 1] * rn;
        uint u0 = __float_as_uint(x0); u0 += 0x7fffu + ((u0 >> 16) & 1u);  // RNE bf16
        uint u1 = __float_as_uint(x1); u1 += 0x7fffu + ((u1 >> 16) & 1u);
        pk[i] = (u0 >> 16) | (u1 & 0xffff0000u);
    }
    uint4* o = (uint4*)(dst + (size_t)P * CC + c0);
#pragma unroll
    for (int k = 0; k < 4; ++k)
        o[k] = make_uint4(pk[4 * k], pk[4 * k + 1], pk[4 * k + 2], pk[4 * k + 3]);
}

// ---------------- kernel 2: bf16 MFMA GEMM + exp + masked row/col sums ----------------
// S[p][q] = sum_c A[p][c]*B[q][c]; tile 128x128, 4 waves (2x2 of 64x64), BK=64, dbuf
__global__ __launch_bounds__(256) void gemm_mfma(
    const ushort* __restrict__ Abf, const ushort* __restrict__ Bbf,
    const int* __restrict__ rmask, const int* __restrict__ imask,
    float* __restrict__ num_r, float* __restrict__ den_r,
    float* __restrict__ num_i, float* __restrict__ den_i)
{
    __shared__ ushort As[2][128][64];
    __shared__ ushort Bs[2][128][64];

    const int n  = blockIdx.z;
    // XCD-aware bijective swizzle within the 32x32 slice (1024 % 8 == 0)
    const int lin = blockIdx.y * 32 + blockIdx.x;
    const int swz = (lin & 7) * 128 + (lin >> 3);
    const int q0 = (swz & 31) * 128;
    const int p0 = (swz >> 5) * 128;

    const int t  = threadIdx.x;
    const int lane = t & 63;
    const int wv = t >> 6, wr = wv >> 1, wc = wv & 1;
    const int kg = lane >> 4, rl = lane & 15;

    const ushort* Ab = Abf + ((size_t)n * HWD + p0) * CC;
    const ushort* Bb = Bbf + ((size_t)n * HWD + q0) * CC;

    f32x4 acc[4][4];
#pragma unroll
    for (int mi = 0; mi < 4; ++mi)
#pragma unroll
        for (int ni = 0; ni < 4; ++ni) acc[mi][ni] = (f32x4){0.f, 0.f, 0.f, 0.f};

    // staging: per matrix per buf: 128 rows x 8 chunks(16B) = 1024 slots.
    // LDS linear (global_load_lds wave-uniform base + lane*16); global chunk
    // pre-swizzled g = pos ^ (r&7); reads undo it -> 2-way max aliasing.
    auto stage = [&](int buf, int c0) {
#pragma unroll
        for (int it = 0; it < 4; ++it) {
            int slot = it * 256 + t;
            int r = slot >> 3, pos = slot & 7;
            int g = pos ^ (r & 7);
            const ushort* ga = Ab + (size_t)r * CC + c0 + g * 8;
            const ushort* gb = Bb + (size_t)r * CC + c0 + g * 8;
            char* la = ((char*)As[buf]) + it * 4096 + (t & 192) * 16;
            char* lb = ((char*)Bs[buf]) + it * 4096 + (t & 192) * 16;
            gload16(ga, la);
            gload16(gb, lb);
        }
    };

    stage(0, 0);
    for (int kt = 0; kt < 4; ++kt) {
        __syncthreads();                        // buf[kt] staged (vmcnt drain)
        if (kt < 3) stage((kt + 1) & 1, (kt + 1) * 64);
        const int buf = kt & 1;
#pragma unroll
        for (int ks = 0; ks < 2; ++ks) {
            bf16x8 a[4], b[4];
#pragma unroll
            for (int mi = 0; mi < 4; ++mi) {
                int r = wr * 64 + mi * 16 + rl;
                int pa = (ks * 4 + kg) ^ (r & 7);
                a[mi] = *(const bf16x8*)&As[buf][r][pa * 8];
            }
#pragma unroll
            for (int ni = 0; ni < 4; ++ni) {
                int r = wc * 64 + ni * 16 + rl;
                int pb = (ks * 4 + kg) ^ (r & 7);
                b[ni] = *(const bf16x8*)&Bs[buf][r][pb * 8];
            }
#pragma unroll
            for (int mi = 0; mi < 4; ++mi)
#pragma unroll
                for (int ni = 0; ni < 4; ++ni)
                    acc[mi][ni] = __builtin_amdgcn_mfma_f32_16x16x32_bf16(a[mi], b[ni], acc[mi][ni], 0, 0, 0);
        }
    }

    // ---- epilogue ----
    // C/D layout: col = q0+wc*64+ni*16+rl ; row = p0+wr*64+mi*16+kg*4+j
    const int* rmp = rmask + (size_t)n * HWD + p0 + wr * 64;
    const int* imp = imask + (size_t)n * HWD + q0 + wc * 64;
    int clab[4];
#pragma unroll
    for (int ni = 0; ni < 4; ++ni) clab[ni] = imp[ni * 16 + rl];

    const float SC = 28.853900817779268f;      // 20 * log2(e)
    float cn[4] = {0.f, 0.f, 0.f, 0.f}, cd[4] = {0.f, 0.f, 0.f, 0.f};

#pragma unroll
    for (int mi = 0; mi < 4; ++mi) {
        int4 r4 = *(const int4*)(rmp + mi * 16 + kg * 4);
        int rlab[4] = {r4.x, r4.y, r4.z, r4.w};
        float rn4[4] = {0.f, 0.f, 0.f, 0.f}, rd4[4] = {0.f, 0.f, 0.f, 0.f};
#pragma unroll
        for (int ni = 0; ni < 4; ++ni) {
#pragma unroll
            for (int j = 0; j < 4; ++j) {
                float s = fminf(fmaxf(acc[mi][ni][j], -1.f), 1.f);
                float e = exp2f(s * SC);
                rd4[j] += e;
                cd[ni] += e;
                bool m = (rlab[j] == clab[ni]);
                rn4[j] += m ? e : 0.f;
                cn[ni] += m ? e : 0.f;
            }
        }
        // row reduction over rl via DPP (VALU pipe); result in rl==15
#pragma unroll
        for (int j = 0; j < 4; ++j) {
            rn4[j] = dpp_rowsum16(rn4[j]);
            rd4[j] = dpp_rowsum16(rd4[j]);
        }
        if (rl == 15) {
            size_t row = (size_t)n * HWD + p0 + wr * 64 + mi * 16 + kg * 4;
#pragma unroll
            for (int j = 0; j < 4; ++j) {
                atomicAdd(&num_r[row + j], rn4[j]);
                atomicAdd(&den_r[row + j], rd4[j]);
            }
        }
    }
#pragma unroll
    for (int ni = 0; ni < 4; ++ni) {
        cn[ni] += __shfl_xor(cn[ni], 16); cn[ni] += __shfl_xor(cn[ni], 32);
        cd[ni] += __shfl_xor(cd[ni], 16); cd[ni] += __shfl_xor(cd[ni], 32);
    }
    if (kg == 0) {
#pragma unroll
        for (int ni = 0; ni < 4; ++ni) {
            size_t col = (size_t)n * HWD + q0 + wc * 64 + ni * 16 + rl;
            atomicAdd(&num_i[col], cn[ni]);
            atomicAdd(&den_i[col], cd[ni]);
        }
    }
}

// ---------------- kernel 3: loss entries + global reduce ----------------
__global__ __launch_bounds__(256) void loss_reduce(
    const float* __restrict__ num_r, const float* __restrict__ den_r,
    const float* __restrict__ num_i, const float* __restrict__ den_i,
    const int* __restrict__ rmask, const int* __restrict__ imask,
    float* __restrict__ accum)
{
    __shared__ float sbuf[2][4];
    int idx = blockIdx.x * 256 + threadIdx.x;   // 0 .. 2*NB*HWD-1
    float num, den; int fg;
    if (idx < NB * HWD) {
        num = num_r[idx]; den = den_r[idx]; fg = rmask[idx] > 0;
    } else {
        int k = idx - NB * HWD;
        num = num_i[k]; den = den_i[k]; fg = imask[k] > 0;
    }
    float v = 0.f, cnt = 0.f;
    if (fg && num > 0.f) {
        float r = num / (den + 1e-6f);
        v = -__logf(r);
        cnt = 1.f;
    }
#pragma unroll
    for (int m = 1; m <= 32; m <<= 1) {
        v += __shfl_xor(v, m);
        cnt += __shfl_xor(cnt, m);
    }
    int lane = threadIdx.x & 63, wave = threadIdx.x >> 6;
    if (lane == 0) { sbuf[0][wave] = v; sbuf[1][wave] = cnt; }
    __syncthreads();
    if (threadIdx.x == 0) {
        atomicAdd(&accum[0], sbuf[0][0] + sbuf[0][1] + sbuf[0][2] + sbuf[0][3]);
        atomicAdd(&accum[1], sbuf[1][0] + sbuf[1][1] + sbuf[1][2] + sbuf[1][3]);
    }
}

__global__ void finalize(const float* __restrict__ accum, float* __restrict__ out) {
    out[0] = accum[0] / fmaxf(accum[1], 1.0f);
}

// ---------------- launch ----------------
extern "C" void kernel_launch(void* const* d_in, const int* in_sizes, int n_in,
                              void* d_out, int out_size, void* d_ws, size_t ws_size,
                              hipStream_t stream) {
    const float* rgb = (const float*)d_in[0];
    const float* ir  = (const float*)d_in[1];
    const int* rm = (const int*)d_in[2];
    const int* im = (const int*)d_in[3];
    float* out = (float*)d_out;

    const size_t NP = (size_t)NB * HWD;          // 16384 pixels
    const size_t NE = NP * CC;                   // 4M bf16 per array
    ushort* Abf = (ushort*)d_ws;
    ushort* Bbf = Abf + NE;
    float* num_r = (float*)(Bbf + NE);
    float* den_r = num_r + NP;
    float* num_i = den_r + NP;
    float* den_i = num_i + NP;
    float* accum = den_i + NP;                   // 2 floats

    hipMemsetAsync(num_r, 0, (4 * NP + 2) * sizeof(float), stream);

    normcvt<<<dim3(NP / 64, 2), 512, 0, stream>>>(rgb, ir, Abf, Bbf);
    gemm_mfma<<<dim3(HWD / 128, HWD / 128, NB), 256, 0, stream>>>(
        Abf, Bbf, rm, im, num_r, den_r, num_i, den_i);
    loss_reduce<<<(2 * NP) / 256, 256, 0, stream>>>(num_r, den_r, num_i, den_i, rm, im, accum);
    finalize<<<1, 1, 0, stream>>>(accum, out);
}